// Round 6
// baseline (4300.600 us; speedup 1.0000x reference)
//
#include <hip/hip_runtime.h>
#include <math.h>

// Sizes (fixed by the problem)
#define BATCH   64
#define SEQ     512
#define NIN     512
#define NHID    1024
#define NOUT    512

typedef unsigned int u32x4 __attribute__((ext_vector_type(4)));

// ---------------- Tiled fp32 GEMM with bias: C[M,N] = A[M,K] @ B[K,N] + bias[N]
#define BM 64
#define BN 64
#define BK 16

__global__ __launch_bounds__(256) void gemm_bias(
    const float* __restrict__ A, const float* __restrict__ B,
    const float* __restrict__ bias, float* __restrict__ C,
    int M, int N, int K) {
  __shared__ float As[BK][BM + 4];
  __shared__ float Bs[BK][BN + 4];

  const int tid = threadIdx.x;
  const int bx = blockIdx.x;
  const int by = blockIdx.y;

  const int tm = (tid / 16) * 4;
  const int tn = (tid % 16) * 4;

  const int ar = tid / 4;
  const int ac = (tid % 4) * 4;
  const int br = tid / 16;
  const int bc = (tid % 16) * 4;

  float acc[4][4] = {};

  for (int k0 = 0; k0 < K; k0 += BK) {
    float4 av = *(const float4*)&A[(size_t)(by * BM + ar) * K + k0 + ac];
    As[ac + 0][ar] = av.x;
    As[ac + 1][ar] = av.y;
    As[ac + 2][ar] = av.z;
    As[ac + 3][ar] = av.w;
    float4 bv = *(const float4*)&B[(size_t)(k0 + br) * N + bx * BN + bc];
    *(float4*)&Bs[br][bc] = bv;
    __syncthreads();

#pragma unroll
    for (int k = 0; k < BK; ++k) {
      float4 a4 = *(const float4*)&As[k][tm];
      float4 b4 = *(const float4*)&Bs[k][tn];
      float ae[4] = {a4.x, a4.y, a4.z, a4.w};
      float be[4] = {b4.x, b4.y, b4.z, b4.w};
#pragma unroll
      for (int i = 0; i < 4; ++i)
#pragma unroll
        for (int j = 0; j < 4; ++j)
          acc[i][j] += ae[i] * be[j];
    }
    __syncthreads();
  }

  const float4 bb = *(const float4*)&bias[bx * BN + tn];
#pragma unroll
  for (int i = 0; i < 4; ++i) {
    float4 o;
    o.x = acc[i][0] + bb.x;
    o.y = acc[i][1] + bb.y;
    o.z = acc[i][2] + bb.z;
    o.w = acc[i][3] + bb.w;
    *(float4*)&C[(size_t)(by * BM + tm + i) * N + bx * BN + tn] = o;
  }
}

// ---------------- Cooperative weight-stationary scan, v6: epoch mailbox ----
// 256 blocks = 8 batch-groups x 32 col-chunks; 256 threads; no barriers.
// h exchanged via a 2-slot ring mailbox of 8B payloads (low32 = f32 h bits,
// high32 = epoch s+1). Writers: ONE agent-scope 8B atomic store per thread.
// Readers: 16 clustered sc0/sc1 dwordx4 loads (one LLC round trip), validate
// all 32 embedded epochs, block-retry via __syncthreads_and. Ring depth 2 is
// safe: a block reaches step s+2 only after ALL blocks wrote s+1, which
// implies all finished reading slot s%2. Per-element validation makes
// ordering assumptions unnecessary.
#define GROUPS 8
#define BPG    32   // blocks per group (column chunks)
#define BPERG  8    // batches per group
#define MB_SLOT  (BPERG * 1024)        // ull elements per slot (64 KB)
#define MB_GROUP (2 * MB_SLOT)         // per group (128 KB)

#define FMA4(hv, wv4, accv)              \
  accv.x = fmaf(hv, wv4.x, accv.x);      \
  accv.y = fmaf(hv, wv4.y, accv.y);      \
  accv.z = fmaf(hv, wv4.z, accv.z);      \
  accv.w = fmaf(hv, wv4.w, accv.w);

__global__ __launch_bounds__(256, 1) void rnn_scan_mb(
    const float* __restrict__ Wh, float* __restrict__ xi,
    unsigned long long* __restrict__ mb) {
  __shared__ float hs[BPERG * NHID];   // 32 KB staged h, XOR-swizzled on k
  __shared__ float P[256 * 32];        // 32 KB partial sums

  const int tid  = threadIdx.x;
  const int bg   = blockIdx.x >> 5;   // 0..7  batch group
  const int jc   = blockIdx.x & 31;   // 0..31 column chunk (32 cols)
  const int c4   = tid & 7;           // column quad within chunk
  const int kseg = tid >> 3;          // 0..31 k-slice (32 k each)
  const int colbase = jc * 32 + c4 * 4;
  const int hswz  = (kseg & 7) << 2;        // read-side LDS swizzle (k bits 5-7)
  const int stswz = ((tid >> 3) & 7) << 2;  // write-side swizzle
  const int ob   = tid >> 5;          // output batch (0..7)
  const int ocol = tid & 31;          // output col within chunk
  const int oc4  = ocol >> 2;
  const int oce  = ocol & 3;

  // Wh sliver in registers: 32 float4 vector loads, fully unrolled.
  float4 w[32];
#pragma unroll
  for (int kk = 0; kk < 32; ++kk)
    w[kk] = *(const float4*)&Wh[(size_t)(kseg * 32 + kk) * NHID + colbase];

  // Thread-private xi column (read xin / write h for the output GEMM).
  float* const xrow_base =
      xi + (size_t)(bg * BPERG + ob) * SEQ * NHID + jc * 32 + ocol;
  unsigned long long* const mb_g = mb + (size_t)bg * MB_GROUP;
  unsigned long long* const wr_base = mb_g + (size_t)ob * 1024 + jc * 32 + ocol;

  for (int s = 0; s < SEQ; ++s) {
    float* prow = xrow_base + (size_t)s * NHID;
    const float xin = *prow;  // thread-private; plain cached load

    float4 acc[BPERG];
#pragma unroll
    for (int b = 0; b < BPERG; ++b) acc[b] = make_float4(0.f, 0.f, 0.f, 0.f);

    if (s > 0) {
      // ---- read phase: fetch h_{s-1} payloads, validate epochs, retry ----
      const unsigned long long* rbase =
          mb_g + (size_t)((s - 1) & 1) * MB_SLOT + tid * 4;
      u32x4 lo[BPERG], hi[BPERG];
      const unsigned int ep = (unsigned int)s;  // h_{s-1} tagged with epoch s
      while (true) {
#pragma unroll
        for (int b = 0; b < BPERG; ++b) {
          asm volatile(
              "global_load_dwordx4 %0, %2, off sc0 sc1\n\t"
              "global_load_dwordx4 %1, %2, off offset:16 sc0 sc1"
              : "=v"(lo[b]), "=v"(hi[b])
              : "v"(rbase + (size_t)b * 1024)
              : "memory");
        }
        asm volatile("s_waitcnt vmcnt(0)" ::: "memory");
        __builtin_amdgcn_sched_barrier(0);
        bool ok = true;
#pragma unroll
        for (int b = 0; b < BPERG; ++b)
          ok = ok && (lo[b].y == ep) && (lo[b].w == ep) &&
               (hi[b].y == ep) && (hi[b].w == ep);
        if (__syncthreads_and((int)ok)) break;
        __builtin_amdgcn_s_sleep(1);
      }
      // Stage h into swizzled LDS (payload low dwords are the h bits).
#pragma unroll
      for (int b = 0; b < BPERG; ++b) {
        float4 v;
        v.x = __uint_as_float(lo[b].x);
        v.y = __uint_as_float(lo[b].z);
        v.z = __uint_as_float(hi[b].x);
        v.w = __uint_as_float(hi[b].z);
        *(float4*)&hs[b * NHID + ((tid * 4) ^ stswz)] = v;
      }
      __syncthreads();

      // Partial matvec over this thread's 32-k slice.
#pragma unroll
      for (int b = 0; b < BPERG; ++b) {
#pragma unroll
        for (int kq = 0; kq < 8; ++kq) {
          const float4 h4 =
              *(const float4*)&hs[b * NHID + kseg * 32 + ((kq * 4) ^ hswz)];
          FMA4(h4.x, w[kq * 4 + 0], acc[b]);
          FMA4(h4.y, w[kq * 4 + 1], acc[b]);
          FMA4(h4.z, w[kq * 4 + 2], acc[b]);
          FMA4(h4.w, w[kq * 4 + 3], acc[b]);
        }
      }
    }

    // Write partials to LDS (bank-swizzled), reduce 32-way per output.
    {
      const int u = kseg * 8 + c4;
      const int sw = (((kseg & 7) ^ c4)) << 2;
#pragma unroll
      for (int b = 0; b < BPERG; ++b)
        *(float4*)&P[u * 32 + ((b * 4) ^ sw)] = acc[b];
    }
    __syncthreads();

    float sum = 0.f;
#pragma unroll
    for (int q = 0; q < 32; ++q) {
      const int uu = q * 8 + oc4;
      const int sw2 = ((q & 7) ^ oc4) << 2;
      sum += P[uu * 32 + ((ob * 4 + oce) ^ sw2)];
    }

    // Activation; publish h via epoch-tagged 8B payload (no barrier!).
    const float hn = fmaxf(tanhf(xin + sum), 0.f);
    *prow = hn;  // for the output GEMM (visible at kernel boundary)
    const unsigned long long pay =
        ((unsigned long long)(unsigned int)(s + 1) << 32) |
        (unsigned long long)__float_as_uint(hn);
    __hip_atomic_store(wr_base + (size_t)(s & 1) * MB_SLOT, pay,
                       __ATOMIC_RELAXED, __HIP_MEMORY_SCOPE_AGENT);
  }
}

extern "C" void kernel_launch(void* const* d_in, const int* in_sizes, int n_in,
                              void* d_out, int out_size, void* d_ws, size_t ws_size,
                              hipStream_t stream) {
  const float* x  = (const float*)d_in[0];  // [64,512,512]
  const float* Wi = (const float*)d_in[1];  // [512,1024]
  const float* bi = (const float*)d_in[2];  // [1024]
  const float* Wh = (const float*)d_in[3];  // [1024,1024]
  const float* Wo = (const float*)d_in[4];  // [1024,512]
  const float* bo = (const float*)d_in[5];  // [512]
  float* out = (float*)d_out;               // [64,512,512]
  float* xi  = (float*)d_ws;                // [64,512,1024] = 128 MB scratch

  // Epoch mailbox in d_out head (8 groups x 2 slots x 8 x 1024 x 8B = 1 MB);
  // zeroed every launch (prevents stale-epoch deadlock across graph replays);
  // overwritten by the final GEMM.
  unsigned long long* mb = (unsigned long long*)d_out;

  const int M = BATCH * SEQ;  // 32768

  dim3 blk(256);
  hipMemsetAsync(mb, 0, (size_t)GROUPS * MB_GROUP * sizeof(unsigned long long),
                 stream);
  // xi = x @ Wi + bi
  gemm_bias<<<dim3(NHID / BN, M / BM), blk, 0, stream>>>(x, Wi, bi, xi, M, NHID, NIN);
  // sequential scan (cooperative: all 256 blocks co-resident)
  {
    const float* Wh_p = Wh;
    float* xi_p = xi;
    unsigned long long* mb_p = mb;
    void* args[3] = {(void*)&Wh_p, (void*)&xi_p, (void*)&mb_p};
    hipLaunchCooperativeKernel((const void*)rnn_scan_mb, dim3(GROUPS * BPG),
                               dim3(256), args, 0, stream);
  }
  // y = h @ Wo + bo
  gemm_bias<<<dim3(NOUT / BN, M / BM), blk, 0, stream>>>(xi, Wo, bo, out, M, NOUT, NHID);
}

// Round 7
// 2768.658 us; speedup vs baseline: 1.5533x; 1.5533x over previous
//
#include <hip/hip_runtime.h>
#include <math.h>

// Sizes (fixed by the problem)
#define BATCH   64
#define SEQ     512
#define NIN     512
#define NHID    1024
#define NOUT    512

// ---------------- Tiled fp32 GEMM with bias: C[M,N] = A[M,K] @ B[K,N] + bias[N]
// BM=128, BN=64, BK=16, 256 threads, 8x4 microtile.
#define BM 128
#define BN 64
#define BK 16

__global__ __launch_bounds__(256) void gemm_bias(
    const float* __restrict__ A, const float* __restrict__ B,
    const float* __restrict__ bias, float* __restrict__ C,
    int M, int N, int K) {
  __shared__ float As[BK][BM + 4];  // transposed A tile
  __shared__ float Bs[BK][BN + 4];

  const int tid = threadIdx.x;
  const int bx = blockIdx.x;  // N tile
  const int by = blockIdx.y;  // M tile

  const int tm = (tid / 16) * 8;   // 0..120, 8 rows
  const int tn = (tid % 16) * 4;   // 0..60, 4 cols

  const int ar = tid / 4;            // 0..63 (+64 second row)
  const int ac = (tid % 4) * 4;      // k 0,4,8,12
  const int br = tid / 16;           // 0..15
  const int bc = (tid % 16) * 4;     // 0..60

  float acc[8][4] = {};

  for (int k0 = 0; k0 < K; k0 += BK) {
    float4 av0 = *(const float4*)&A[(size_t)(by * BM + ar) * K + k0 + ac];
    float4 av1 = *(const float4*)&A[(size_t)(by * BM + ar + 64) * K + k0 + ac];
    As[ac + 0][ar] = av0.x;  As[ac + 0][ar + 64] = av1.x;
    As[ac + 1][ar] = av0.y;  As[ac + 1][ar + 64] = av1.y;
    As[ac + 2][ar] = av0.z;  As[ac + 2][ar + 64] = av1.z;
    As[ac + 3][ar] = av0.w;  As[ac + 3][ar + 64] = av1.w;
    float4 bv = *(const float4*)&B[(size_t)(k0 + br) * N + bx * BN + bc];
    *(float4*)&Bs[br][bc] = bv;
    __syncthreads();

#pragma unroll
    for (int k = 0; k < BK; ++k) {
      float4 a0 = *(const float4*)&As[k][tm];
      float4 a1 = *(const float4*)&As[k][tm + 4];
      float4 b4 = *(const float4*)&Bs[k][tn];
      float ae[8] = {a0.x, a0.y, a0.z, a0.w, a1.x, a1.y, a1.z, a1.w};
      float be[4] = {b4.x, b4.y, b4.z, b4.w};
#pragma unroll
      for (int i = 0; i < 8; ++i)
#pragma unroll
        for (int j = 0; j < 4; ++j)
          acc[i][j] = fmaf(ae[i], be[j], acc[i][j]);
    }
    __syncthreads();
  }

  const float4 bb = *(const float4*)&bias[bx * BN + tn];
#pragma unroll
  for (int i = 0; i < 8; ++i) {
    float4 o;
    o.x = acc[i][0] + bb.x;
    o.y = acc[i][1] + bb.y;
    o.z = acc[i][2] + bb.z;
    o.w = acc[i][3] + bb.w;
    *(float4*)&C[(size_t)(by * BM + tm + i) * N + bx * BN + tn] = o;
  }
}

// ---------------- Cooperative weight-stationary scan, v7 ----------------
// = v5 (proven: flag barrier, plain L2-cacheable staging, bypassing xin /
// h-store) + XCD co-location: bg = blockIdx&7 so all 32 blocks of a batch
// group land on one XCD under round-robin dispatch -> staging loads share
// one MALL->L2 fill per group per step. Correctness is mapping-independent.
#define GROUPS 8
#define BPG    32   // blocks per group (column chunks)
#define BPERG  8    // batches per group

#define FMA4(hv, wv4, accv)              \
  accv.x = fmaf(hv, wv4.x, accv.x);      \
  accv.y = fmaf(hv, wv4.y, accv.y);      \
  accv.z = fmaf(hv, wv4.z, accv.z);      \
  accv.w = fmaf(hv, wv4.w, accv.w);

__global__ __launch_bounds__(256, 1) void rnn_scan_ws(
    const float* __restrict__ Wh, float* __restrict__ xi,
    unsigned int* flags) {
  __shared__ float hs[BPERG * NHID];   // 32 KB staged h, XOR-swizzled on k
  __shared__ float P[256 * 32];        // 32 KB partial sums

  const int tid  = threadIdx.x;
  const int bg   = blockIdx.x & 7;    // XCD id under round-robin dispatch
  const int jc   = blockIdx.x >> 3;   // 0..31 column chunk (32 cols)
  const int c4   = tid & 7;           // column quad within chunk
  const int kseg = tid >> 3;          // 0..31 k-slice (32 k each)
  const int colbase = jc * 32 + c4 * 4;
  const int hswz  = (kseg & 7) << 2;        // read-side LDS swizzle (k bits 5-7)
  const int stswz = ((tid >> 3) & 7) << 2;  // write-side swizzle
  const int ob   = tid >> 5;          // output batch (0..7)
  const int ocol = tid & 31;          // output col within chunk
  const int oc4  = ocol >> 2;
  const int oce  = ocol & 3;

  // Wh sliver in registers: 32 float4 vector loads, fully unrolled.
  float4 w[32];
#pragma unroll
  for (int kk = 0; kk < 32; ++kk)
    w[kk] = *(const float4*)&Wh[(size_t)(kseg * 32 + kk) * NHID + colbase];

  // This thread's xi/h column pointer.
  float* const xrow_base =
      xi + (size_t)(bg * BPERG + ob) * SEQ * NHID + jc * 32 + ocol;
  // Per-group flag region: 32 uints (128B), regions disjoint per group.
  unsigned int* const gflags = flags + bg * 32;
  unsigned int* const myflag = gflags + jc;
  unsigned int* const pollflag = gflags + (tid & 31);

  for (int s = 0; s < SEQ; ++s) {
    // Step input (pre-activation xi): agent-scope bypassing load so the
    // pre-finalization line is NEVER cached in L1/L2. Issued early; its
    // latency hides under staging/matvec.
    float* prow = xrow_base + (size_t)s * NHID;
    const float xin = __hip_atomic_load(prow, __ATOMIC_RELAXED,
                                        __HIP_MEMORY_SCOPE_AGENT);

    float4 acc[BPERG];
#pragma unroll
    for (int b = 0; b < BPERG; ++b) acc[b] = make_float4(0.f, 0.f, 0.f, 0.f);

    if (s > 0) {
      // Stage h_{s-1} (8 rows x 1024) into swizzled LDS: plain float4 loads,
      // clustered, all in flight simultaneously. Safe: these lines are never
      // cached pre-finalization (flag order; xin/h-store bypass L1/L2), and
      // with co-location most blocks hit the XCD-local L2 fill.
      const float* base =
          xi + (size_t)(bg * BPERG) * SEQ * NHID + (size_t)(s - 1) * NHID + tid * 4;
#pragma unroll
      for (int b = 0; b < BPERG; ++b) {
        float4 v = *(const float4*)(base + (size_t)b * SEQ * NHID);
        *(float4*)&hs[b * NHID + ((tid * 4) ^ stswz)] = v;
      }
      __syncthreads();

      // Partial matvec over this thread's 32-k slice.
#pragma unroll
      for (int b = 0; b < BPERG; ++b) {
#pragma unroll
        for (int kq = 0; kq < 8; ++kq) {
          const float4 h4 =
              *(const float4*)&hs[b * NHID + kseg * 32 + ((kq * 4) ^ hswz)];
          FMA4(h4.x, w[kq * 4 + 0], acc[b]);
          FMA4(h4.y, w[kq * 4 + 1], acc[b]);
          FMA4(h4.z, w[kq * 4 + 2], acc[b]);
          FMA4(h4.w, w[kq * 4 + 3], acc[b]);
        }
      }
    }

    // Write partials to LDS (bank-swizzled), reduce 32-way per output.
    {
      const int u = kseg * 8 + c4;
      const int sw = (((kseg & 7) ^ c4)) << 2;
#pragma unroll
      for (int b = 0; b < BPERG; ++b)
        *(float4*)&P[u * 32 + ((b * 4) ^ sw)] = acc[b];
    }
    __syncthreads();

    float sum = 0.f;
#pragma unroll
    for (int q = 0; q < 32; ++q) {
      const int uu = q * 8 + oc4;
      const int sw2 = ((q & 7) ^ oc4) << 2;
      sum += P[uu * 32 + ((ob * 4 + oce) ^ sw2)];
    }

    // Activation + in-place store of h_s (agent-scope, write-through).
    const float hn = fmaxf(tanhf(xin + sum), 0.f);
    __hip_atomic_store(prow, hn, __ATOMIC_RELAXED, __HIP_MEMORY_SCOPE_AGENT);

    // ---- group barrier: epoch flags, no RMW ----
    // syncthreads drains vmcnt(0): h stores are at the coherence point
    // before the flag store issues.
    __syncthreads();
    const unsigned int target = (unsigned int)(s + 1);
    if (tid == 0)
      __hip_atomic_store(myflag, target, __ATOMIC_RELAXED,
                         __HIP_MEMORY_SCOPE_AGENT);
    if (tid < 64) {
      // Whole wave 0 polls: lane j reads flag j (lanes 32-63 duplicate).
      while (true) {
        unsigned int v = __hip_atomic_load(pollflag, __ATOMIC_RELAXED,
                                           __HIP_MEMORY_SCOPE_AGENT);
        if (__all(v >= target)) break;
        __builtin_amdgcn_s_sleep(1);
      }
    }
    __syncthreads();
  }
}

extern "C" void kernel_launch(void* const* d_in, const int* in_sizes, int n_in,
                              void* d_out, int out_size, void* d_ws, size_t ws_size,
                              hipStream_t stream) {
  const float* x  = (const float*)d_in[0];  // [64,512,512]
  const float* Wi = (const float*)d_in[1];  // [512,1024]
  const float* bi = (const float*)d_in[2];  // [1024]
  const float* Wh = (const float*)d_in[3];  // [1024,1024]
  const float* Wo = (const float*)d_in[4];  // [1024,512]
  const float* bo = (const float*)d_in[5];  // [512]
  float* out = (float*)d_out;               // [64,512,512]
  float* xi  = (float*)d_ws;                // [64,512,1024] = 128 MB scratch

  // Epoch flags in d_out head (8 groups x 32 x 4B = 1KB);
  // overwritten by the final GEMM. Zeroed every launch.
  unsigned int* flags = (unsigned int*)d_out;

  const int M = BATCH * SEQ;  // 32768

  dim3 blk(256);
  hipMemsetAsync(flags, 0, GROUPS * BPG * sizeof(unsigned int), stream);
  // xi = x @ Wi + bi
  gemm_bias<<<dim3(NHID / BN, M / BM), blk, 0, stream>>>(x, Wi, bi, xi, M, NHID, NIN);
  // sequential scan (cooperative: all 256 blocks co-resident)
  {
    const float* Wh_p = Wh;
    float* xi_p = xi;
    unsigned int* flags_p = flags;
    void* args[3] = {(void*)&Wh_p, (void*)&xi_p, (void*)&flags_p};
    hipLaunchCooperativeKernel((const void*)rnn_scan_ws, dim3(GROUPS * BPG),
                               dim3(256), args, 0, stream);
  }
  // y = h @ Wo + bo
  gemm_bias<<<dim3(NOUT / BN, M / BM), blk, 0, stream>>>(xi, Wo, bo, out, M, NOUT, NHID);
}